// Round 2
// baseline (525.827 us; speedup 1.0000x reference)
//
#include <hip/hip_runtime.h>
#include <math.h>

#define DDIM 4096
#define EXPERTS 64
#define TT 64          // tokens per block
#define KT 64          // k per tile
#define KHALF 2048     // k per wave-set
#define NT (KHALF / KT)

typedef float f32x16 __attribute__((ext_vector_type(16)));

// async global->LDS, 16B/lane, wave-uniform LDS base (HW adds lane*16)
__device__ __forceinline__ void gload_lds16(const void* g, void* l) {
  __builtin_amdgcn_global_load_lds(
      (const __attribute__((address_space(1))) void*)g,
      (__attribute__((address_space(3))) void*)l, 16, 0, 0);
}

// stage one 64x64 f32 x-tile into LDS. Source is pre-swizzled so that
// LDS(row r, slot s) holds x[r][quad s^(r&7)] -> swizzled reads are linear.
// 16 chunks of 1KiB; the 4 waves of this k-set stage 4 chunks each.
__device__ __forceinline__ void stage_x(const float* __restrict__ gx,
                                        float* ldsbuf, int lane, int wsub) {
#pragma unroll
  for (int j = 0; j < 4; ++j) {
    const int c = wsub * 4 + j;
    const int r = 4 * c + (lane >> 4);
    const int s = (lane & 15) ^ (r & 7);
    gload_lds16(gx + (size_t)r * DDIM + (s << 2), ldsbuf + c * 256);
  }
}

__global__ __launch_bounds__(512) void moe_gate_main(
    const float* __restrict__ x,    // [N][4096]
    const float* __restrict__ wT,   // [4096][64]
    float* __restrict__ out,        // idx [N*8], w [N*8], aux
    float* __restrict__ pi_g,       // [64]
    float* __restrict__ ce_g,       // [64]
    int N) {
  __shared__ float smem[16384];   // 64 KiB: 4 x-tile buffers [kset][dbuf]
  float* lt = smem;               // epilogue: logits [64 e][stride 68]
  float* inv_s = smem + 4352;
  float* ce_lds = smem + 4416;

  const int tid = threadIdx.x;
  const int lane = tid & 63;           // token within block
  const int wv = tid >> 6;             // wave 0..7
  const int kset = wv >> 2;            // k-half owner
  const int wsub = wv & 3;             // expert quartet within k-set
  const int e0u = __builtin_amdgcn_readfirstlane(wsub << 4);  // 16 e / wave
  const int token0 = blockIdx.x * TT;
  const int s7 = lane & 7;

  float acc[16];
#pragma unroll
  for (int i = 0; i < 16; ++i) acc[i] = 0.f;

  const float* gx = x + (size_t)token0 * DDIM + kset * KHALF;
  const float* wb0 = wT + (size_t)kset * KHALF * EXPERTS + e0u;

  float* buf0 = smem + (kset * 2) * 4096;
  float* buf1 = smem + (kset * 2 + 1) * 4096;

  stage_x(gx, buf0, lane, wsub);
  asm volatile("s_waitcnt vmcnt(0)" ::: "memory");
  __syncthreads();

#pragma unroll 1
  for (int kt = 0; kt < NT; ++kt) {
    const float* bufc = (kt & 1) ? buf1 : buf0;
    if (kt + 1 < NT)
      stage_x(gx + (kt + 1) * KT, (kt & 1) ? buf0 : buf1, lane, wsub);

    const float* xrow = bufc + lane * 64;
    const float* wk0 = wb0 + (size_t)kt * KT * EXPERTS;
#pragma unroll
    for (int q = 0; q < 16; ++q) {
      const float4 xq = *(const float4*)(xrow + ((q ^ s7) << 2));
      const float* wk = wk0 + q * 4 * EXPERTS;
      const f32x16 w0 = *(const f32x16*)(wk);
      const f32x16 w1 = *(const f32x16*)(wk + EXPERTS);
      const f32x16 w2 = *(const f32x16*)(wk + 2 * EXPERTS);
      const f32x16 w3 = *(const f32x16*)(wk + 3 * EXPERTS);
#pragma unroll
      for (int i = 0; i < 16; ++i) {
        acc[i] = fmaf(xq.x, w0[i], acc[i]);
        acc[i] = fmaf(xq.y, w1[i], acc[i]);
        acc[i] = fmaf(xq.z, w2[i], acc[i]);
        acc[i] = fmaf(xq.w, w3[i], acc[i]);
      }
    }
    asm volatile("s_waitcnt vmcnt(0)" ::: "memory");
    __syncthreads();
  }

  // ---- combine k-half partials into lt[expert*68 + token] ----
  if (kset == 0) {
#pragma unroll
    for (int i = 0; i < 16; ++i) lt[(e0u + i) * 68 + lane] = acc[i];
  }
  __syncthreads();
  if (kset == 1) {
#pragma unroll
    for (int i = 0; i < 16; ++i) lt[(e0u + i) * 68 + lane] += acc[i];
  }
  __syncthreads();

  // ---- softmax per token (store p = exp(l-m) back) ----
  if (tid < 64) {
    const int t = tid;
    ce_lds[t] = 0.f;
    float m = -1e30f;
#pragma unroll 1
    for (int e = 0; e < 64; ++e) m = fmaxf(m, lt[e * 68 + t]);
    float ssum = 0.f;
#pragma unroll 1
    for (int e = 0; e < 64; ++e) {
      float p = expf(lt[e * 68 + t] - m);
      lt[e * 68 + t] = p;
      ssum += p;
    }
    inv_s[t] = 1.f / ssum;
  }
  __syncthreads();

  // ---- pi partial: per-expert sum of scores ----
  if (tid < 64) {
    const int e = tid;
    float s = 0.f;
#pragma unroll 1
    for (int t = 0; t < 64; ++t) s += lt[e * 68 + t] * inv_s[t];
    atomicAdd(pi_g + e, s);
  }
  __syncthreads();

  // ---- stable top-8 (strict > keeps lowest index on ties) ----
  if (tid < 64) {
    const int t = tid;
    const float invv = inv_s[t];
    const size_t tg = (size_t)(token0 + t);
#pragma unroll 1
    for (int r = 0; r < 8; ++r) {
      float bv = -1.f; int bi = 0;
#pragma unroll 1
      for (int e = 0; e < 64; ++e) {
        float p = lt[e * 68 + t];
        if (p > bv) { bv = p; bi = e; }
      }
      lt[bi * 68 + t] = -1.f;
      atomicAdd(ce_lds + bi, 1.f);
      out[tg * 8 + r] = (float)bi;
      out[(size_t)N * 8 + tg * 8 + r] = bv * invv;
    }
  }
  __syncthreads();
  if (tid < 64) atomicAdd(ce_g + tid, ce_lds[tid]);
}

// ---- w [64][4096] -> wT [4096][64] ----
__global__ void transpose_w(const float* __restrict__ w, float* __restrict__ wt) {
  __shared__ float t[32][33];
  const int k0 = blockIdx.x << 5;
  const int e0 = blockIdx.y << 5;
  const int tx = threadIdx.x;  // 0..31
  const int ty = threadIdx.y;  // 0..7
#pragma unroll
  for (int i = ty; i < 32; i += 8)
    t[i][tx] = w[(size_t)(e0 + i) * DDIM + k0 + tx];
  __syncthreads();
#pragma unroll
  for (int i = ty; i < 32; i += 8)
    wt[(size_t)(k0 + i) * EXPERTS + e0 + tx] = t[tx][i];
}

__global__ void aux_final(const float* __restrict__ pi_g,
                          const float* __restrict__ ce_g,
                          float* __restrict__ out_aux, int N) {
  const int e = threadIdx.x;  // 64
  float v = (pi_g[e] / (float)N) * (ce_g[e] / ((float)N * 8.0f)) * 64.0f * 0.01f;
#pragma unroll
  for (int off = 32; off; off >>= 1) v += __shfl_down(v, off, 64);
  if (e == 0) *out_aux = v;
}

extern "C" void kernel_launch(void* const* d_in, const int* in_sizes, int n_in,
                              void* d_out, int out_size, void* d_ws, size_t ws_size,
                              hipStream_t stream) {
  (void)n_in; (void)out_size; (void)ws_size;
  const float* x = (const float*)d_in[0];
  const float* w = (const float*)d_in[1];
  float* out = (float*)d_out;
  const int N = in_sizes[0] / DDIM;  // 16384

  float* wT = (float*)d_ws;                    // 4096*64 floats = 1 MiB
  float* pi_g = wT + (size_t)DDIM * EXPERTS;   // 64 floats
  float* ce_g = pi_g + 64;                     // 64 floats

  hipMemsetAsync(pi_g, 0, 128 * sizeof(float), stream);
  transpose_w<<<dim3(DDIM / 32, EXPERTS / 32), dim3(32, 8), 0, stream>>>(w, wT);
  moe_gate_main<<<N / TT, 512, 0, stream>>>(x, wT, out, pi_g, ce_g, N);
  aux_final<<<1, 64, 0, stream>>>(pi_g, ce_g, out + (size_t)N * 16, N);
}

// Round 3
// 151.744 us; speedup vs baseline: 3.4652x; 3.4652x over previous
//
#include <hip/hip_runtime.h>
#include <math.h>

#define DDIM 4096
#define NEXP 64
#define NKB 128  // K tiles of 32

typedef short s16x8 __attribute__((ext_vector_type(8)));
typedef float f32x4 __attribute__((ext_vector_type(4)));

__device__ __forceinline__ unsigned cvt_pk_bf16(float a, float b) {
  unsigned r;
  asm("v_cvt_pk_bf16_f32 %0, %1, %2" : "=v"(r) : "v"(a), "v"(b));
  return r;  // lo16 = bf16(a), hi16 = bf16(b)
}

// 3-way bf16 split of two floats -> packed hi/mid/lo words
__device__ __forceinline__ void split2(float a, float b, unsigned& H,
                                       unsigned& M, unsigned& L) {
  H = cvt_pk_bf16(a, b);
  float h0 = __uint_as_float(H << 16);
  float h1 = __uint_as_float(H & 0xffff0000u);
  float r0 = a - h0, r1 = b - h1;
  M = cvt_pk_bf16(r0, r1);
  float m0 = __uint_as_float(M << 16);
  float m1 = __uint_as_float(M & 0xffff0000u);
  L = cvt_pk_bf16(r0 - m0, r1 - m1);
}

union U8 {
  unsigned u[4];
  s16x8 v;
};
__device__ __forceinline__ s16x8 pack8(const unsigned* a) {
  U8 t;
  t.u[0] = a[0]; t.u[1] = a[1]; t.u[2] = a[2]; t.u[3] = a[3];
  return t.v;
}

// stage this wave's 3 of the 12 1KB B-fragment chunks for k-tile kb
__device__ __forceinline__ void stage3(const ushort* __restrict__ wf, int kb,
                                       char* dst, int wv, int lane) {
#pragma unroll
  for (int j = 0; j < 3; ++j) {
    const int c = wv * 3 + j;
    __builtin_amdgcn_global_load_lds(
        (const __attribute__((address_space(1))) void*)(wf + (size_t)(kb * 12 + c) * 512 + lane * 8),
        (__attribute__((address_space(3))) void*)(dst + c * 1024), 16, 0, 0);
  }
}

#define MFMA(A, B, C) __builtin_amdgcn_mfma_f32_16x16x32_bf16(A, B, C, 0, 0, 0)

__global__ __launch_bounds__(256, 1) void moe_gate_main(
    const float* __restrict__ x,    // [N][4096]
    const ushort* __restrict__ wf,  // [128kb][4eg][3lvl][64lane][8] bf16 bits
    float* __restrict__ out,        // idx [N*8], w [N*8], aux
    float* __restrict__ pi_g, float* __restrict__ ce_g, int N) {
  __shared__ float smem[6656];  // 26 KB: GEMM = 2x12KB B dbuf; epilogue = lt etc.
  float* lt = smem;             // logits [64 e][stride 68]
  float* inv_s = smem + 4352;
  float* ce_lds = smem + 4416;
  char* bbuf = (char*)smem;

  const int tid = threadIdx.x;
  const int lane = tid & 63;
  const int wv = tid >> 6;  // wave = 16-token group, all 64 experts
  const int tok0 = blockIdx.x << 6;
  const float* xr = x + (size_t)(tok0 + (wv << 4) + (lane & 15)) * DDIM +
                    ((lane >> 4) << 3);

  f32x4 accH[4], accS[4], accC[4];
#pragma unroll
  for (int eg = 0; eg < 4; ++eg) {
#pragma unroll
    for (int r = 0; r < 4; ++r) { accH[eg][r] = 0.f; accS[eg][r] = 0.f; accC[eg][r] = 0.f; }
  }

  // prologue (FIFO order: x(0), s(0), x(1), s(1))
  float4 xa0 = ((const float4*)xr)[0];
  float4 xb0 = ((const float4*)xr)[1];
  stage3(wf, 0, bbuf, wv, lane);
  float4 xa1 = ((const float4*)(xr + 32))[0];
  float4 xb1 = ((const float4*)(xr + 32))[1];
  stage3(wf, 1, bbuf + 12288, wv, lane);

#define GBODY(XA, XB, PAR, KB)                                                 \
  {                                                                            \
    asm volatile("s_waitcnt vmcnt(5)" ::: "memory");                           \
    __builtin_amdgcn_s_barrier();                                              \
    unsigned AH[4], AM[4], AL[4];                                              \
    split2(XA.x, XA.y, AH[0], AM[0], AL[0]);                                   \
    split2(XA.z, XA.w, AH[1], AM[1], AL[1]);                                   \
    split2(XB.x, XB.y, AH[2], AM[2], AL[2]);                                   \
    split2(XB.z, XB.w, AH[3], AM[3], AL[3]);                                   \
    s16x8 ah = pack8(AH), am = pack8(AM), al = pack8(AL);                      \
    {                                                                          \
      int kn = (KB) + 2 > 127 ? 127 : (KB) + 2;                                \
      XA = ((const float4*)(xr + kn * 32))[0];                                 \
      XB = ((const float4*)(xr + kn * 32))[1];                                 \
    }                                                                          \
    const char* bb = bbuf + (PAR)*12288 + lane * 16;                           \
    _Pragma("unroll") for (int eg = 0; eg < 4; ++eg) {                         \
      s16x8 bh = *(const s16x8*)(bb + (eg * 3 + 0) * 1024);                    \
      s16x8 bm = *(const s16x8*)(bb + (eg * 3 + 1) * 1024);                    \
      s16x8 bl = *(const s16x8*)(bb + (eg * 3 + 2) * 1024);                    \
      accH[eg] = MFMA(ah, bh, accH[eg]);                                       \
      accC[eg] = MFMA(ah, bm, accC[eg]);                                       \
      accC[eg] = MFMA(am, bh, accC[eg]);                                       \
      accC[eg] = MFMA(am, bm, accC[eg]);                                       \
      accC[eg] = MFMA(ah, bl, accC[eg]);                                       \
      accC[eg] = MFMA(al, bh, accC[eg]);                                       \
    }                                                                          \
    __builtin_amdgcn_s_barrier();                                              \
    {                                                                          \
      int kn = (KB) + 2 > 127 ? 127 : (KB) + 2;                                \
      stage3(wf, kn, bbuf + (PAR)*12288, wv, lane);                            \
    }                                                                          \
  }

#pragma unroll 1
  for (int kb = 0; kb < NKB; kb += 2) {
    GBODY(xa0, xb0, 0, kb);
    GBODY(xa1, xb1, 1, kb + 1);
    if (((kb + 1) & 31) == 31) {  // drain HH chain every 32 k-tiles
#pragma unroll
      for (int eg = 0; eg < 4; ++eg) {
#pragma unroll
        for (int r = 0; r < 4; ++r) { accS[eg][r] += accH[eg][r]; accH[eg][r] = 0.f; }
      }
    }
  }

  asm volatile("s_waitcnt vmcnt(0)" ::: "memory");
  __syncthreads();

  // logits -> lt[expert*68 + token], unscale by 1/64
#pragma unroll
  for (int eg = 0; eg < 4; ++eg) {
#pragma unroll
    for (int r = 0; r < 4; ++r) {
      float z = (accS[eg][r] + accC[eg][r]) * 0.015625f;
      lt[(eg * 16 + (lane & 15)) * 68 + (wv << 4) + ((lane >> 4) << 2) + r] = z;
    }
  }
  __syncthreads();

  // softmax per token (store p = exp(l-m) back)
  if (tid < 64) {
    const int t = tid;
    ce_lds[t] = 0.f;
    float m = -1e30f;
#pragma unroll 1
    for (int e = 0; e < 64; ++e) m = fmaxf(m, lt[e * 68 + t]);
    float ssum = 0.f;
#pragma unroll 1
    for (int e = 0; e < 64; ++e) {
      float p = expf(lt[e * 68 + t] - m);
      lt[e * 68 + t] = p;
      ssum += p;
    }
    inv_s[t] = 1.f / ssum;
  }
  __syncthreads();

  // pi partial: per-expert sum of scores
  if (tid < 64) {
    const int e = tid;
    float s = 0.f;
#pragma unroll 1
    for (int t = 0; t < 64; ++t) s += lt[e * 68 + t] * inv_s[t];
    atomicAdd(pi_g + e, s);
  }
  __syncthreads();

  // stable top-8 (strict > keeps lowest index on ties; descending like lax.top_k)
  if (tid < 64) {
    const int t = tid;
    const float invv = inv_s[t];
    const size_t tg = (size_t)(tok0 + t);
#pragma unroll 1
    for (int r = 0; r < 8; ++r) {
      float bv = -1.f;
      int bi = 0;
#pragma unroll 1
      for (int e = 0; e < 64; ++e) {
        float p = lt[e * 68 + t];
        if (p > bv) { bv = p; bi = e; }
      }
      lt[bi * 68 + t] = -1.f;
      atomicAdd(ce_lds + bi, 1.f);
      out[tg * 8 + r] = (float)bi;
      out[(size_t)N * 8 + tg * 8 + r] = bv * invv;
    }
  }
  __syncthreads();
  if (tid < 64) atomicAdd(ce_g + tid, ce_lds[tid]);
}

// w [64][4096] -> fragment-ordered 3-way split blob, scaled by 64
__global__ void build_wfrag(const float* __restrict__ w, ushort* __restrict__ wf) {
  const int kb = blockIdx.x;  // 0..127
  const int t = threadIdx.x;  // 256
  const int eg = t >> 6, lane = t & 63;
  const int e = (eg << 4) + (lane & 15);
  const int k0 = (kb << 5) + ((lane >> 4) << 3);
  const float* src = w + (size_t)e * DDIM + k0;
  unsigned H[4], M[4], L[4];
#pragma unroll
  for (int i = 0; i < 4; ++i) {
    float a = src[2 * i] * 64.f, b = src[2 * i + 1] * 64.f;
    split2(a, b, H[i], M[i], L[i]);
  }
  const size_t base = ((size_t)kb * 12 + eg * 3) * 512 + (size_t)lane * 8;
  *(uint4*)(wf + base) = make_uint4(H[0], H[1], H[2], H[3]);
  *(uint4*)(wf + base + 512) = make_uint4(M[0], M[1], M[2], M[3]);
  *(uint4*)(wf + base + 1024) = make_uint4(L[0], L[1], L[2], L[3]);
}

__global__ void aux_final(const float* __restrict__ pi_g,
                          const float* __restrict__ ce_g,
                          float* __restrict__ out_aux, int N) {
  const int e = threadIdx.x;  // 64
  float v = (pi_g[e] / (float)N) * (ce_g[e] / ((float)N * 8.0f)) * 64.0f * 0.01f;
#pragma unroll
  for (int off = 32; off; off >>= 1) v += __shfl_down(v, off, 64);
  if (e == 0) *out_aux = v;
}

extern "C" void kernel_launch(void* const* d_in, const int* in_sizes, int n_in,
                              void* d_out, int out_size, void* d_ws, size_t ws_size,
                              hipStream_t stream) {
  (void)n_in; (void)out_size; (void)ws_size;
  const float* x = (const float*)d_in[0];
  const float* w = (const float*)d_in[1];
  float* out = (float*)d_out;
  const int N = in_sizes[0] / DDIM;  // 16384

  ushort* wf = (ushort*)d_ws;  // 128*12*512 ushorts = 1.5 MiB
  float* pi_g = (float*)((char*)d_ws + (size_t)128 * 12 * 512 * 2);
  float* ce_g = pi_g + 64;

  hipMemsetAsync(pi_g, 0, 128 * sizeof(float), stream);
  build_wfrag<<<128, 256, 0, stream>>>(w, wf);
  moe_gate_main<<<N / 64, 256, 0, stream>>>(x, wf, out, pi_g, ce_g, N);
  aux_final<<<1, 64, 0, stream>>>(pi_g, ce_g, out + (size_t)N * 16, N);
}

// Round 4
// 119.007 us; speedup vs baseline: 4.4185x; 1.2751x over previous
//
#include <hip/hip_runtime.h>
#include <math.h>

#define DDIM 4096
#define NEXP 64

typedef short s16x8 __attribute__((ext_vector_type(8)));
typedef float f32x4 __attribute__((ext_vector_type(4)));

__device__ __forceinline__ unsigned cvt_pk_bf16(float a, float b) {
  unsigned r;
  asm("v_cvt_pk_bf16_f32 %0, %1, %2" : "=v"(r) : "v"(a), "v"(b));
  return r;  // lo16 = bf16(a), hi16 = bf16(b)
}

// 3-way bf16 split of two floats -> packed hi/mid/lo words
__device__ __forceinline__ void split2(float a, float b, unsigned& H,
                                       unsigned& M, unsigned& L) {
  H = cvt_pk_bf16(a, b);
  float h0 = __uint_as_float(H << 16);
  float h1 = __uint_as_float(H & 0xffff0000u);
  float r0 = a - h0, r1 = b - h1;
  M = cvt_pk_bf16(r0, r1);
  float m0 = __uint_as_float(M << 16);
  float m1 = __uint_as_float(M & 0xffff0000u);
  L = cvt_pk_bf16(r0 - m0, r1 - m1);
}

union U8 { unsigned u[4]; s16x8 v; };
__device__ __forceinline__ s16x8 pack8(const unsigned* a) {
  U8 t;
  t.u[0] = a[0]; t.u[1] = a[1]; t.u[2] = a[2]; t.u[3] = a[3];
  return t.v;
}

// stage this sub-wave's 3 of the 12 1KB B-fragment chunks for k-tile kb
__device__ __forceinline__ void stage3(const ushort* __restrict__ wf, int kb,
                                       char* dst, int sw, int lane) {
#pragma unroll
  for (int j = 0; j < 3; ++j) {
    const int c = sw * 3 + j;
    __builtin_amdgcn_global_load_lds(
        (const __attribute__((address_space(1))) void*)(wf + (size_t)(kb * 12 + c) * 512 + lane * 8),
        (__attribute__((address_space(3))) void*)(dst + c * 1024), 16, 0, 0);
  }
}

#define MFMA(A, B, C) __builtin_amdgcn_mfma_f32_16x16x32_bf16(A, B, C, 0, 0, 0)

// 16 waves: group g = wv>>2 owns k-range [g*1024, (g+1)*1024); sub-wave
// s = wv&3 owns tokens [s*16, s*16+16). Each group double-buffers its own
// 12KB B tile in LDS. x loaded global->VGPR 4 k-tiles deep.
__global__ __launch_bounds__(1024) void moe_gate_main(
    const float* __restrict__ x,    // [N][4096]
    const ushort* __restrict__ wf,  // [128kb][4eg][3lvl][64lane][8] bf16 bits
    float* __restrict__ out,        // idx [N*8], w [N*8], aux
    float* __restrict__ pi_g, float* __restrict__ ce_g, int N) {
  __shared__ float smem[24576];  // 96 KB: GEMM = 4 groups x 2 x 12KB
  float* lt = smem;              // epilogue: final logits [64 e][stride 68]
  float* inv_s = smem + 17408;
  float* ce_lds = smem + 17472;

  const int tid = threadIdx.x;
  const int lane = tid & 63;
  const int wv = tid >> 6;   // 0..15
  const int g = wv >> 2;     // k-group
  const int sw = wv & 3;     // token sub-group
  const int tok0 = blockIdx.x << 6;

  char* gbuf = (char*)smem + g * 24576;  // this group's 2x12KB
  const float* xr = x + (size_t)(tok0 + (sw << 4) + (lane & 15)) * DDIM +
                    (g << 10) + ((lane >> 4) << 3);
  const ushort* wfg = wf + (size_t)g * 32 * 12 * 512;

  f32x4 accH[4], accC[4];
#pragma unroll
  for (int eg = 0; eg < 4; ++eg) {
#pragma unroll
    for (int r = 0; r < 4; ++r) { accH[eg][r] = 0.f; accC[eg][r] = 0.f; }
  }

  // prologue, FIFO order: S0, X0, X1, S1, X2, X3
  stage3(wfg, 0, gbuf, sw, lane);
  asm volatile("" ::: "memory");
  float4 x0a = ((const float4*)xr)[0];
  float4 x0b = ((const float4*)xr)[1];
  float4 x1a = ((const float4*)(xr + 32))[0];
  float4 x1b = ((const float4*)(xr + 32))[1];
  asm volatile("" ::: "memory");
  stage3(wfg, 1, gbuf + 12288, sw, lane);
  asm volatile("" ::: "memory");
  float4 x2a = ((const float4*)(xr + 64))[0];
  float4 x2b = ((const float4*)(xr + 64))[1];
  float4 x3a = ((const float4*)(xr + 96))[0];
  float4 x3b = ((const float4*)(xr + 96))[1];
  asm volatile("" ::: "memory");

#define GBODY(XA, XB, PAR, I)                                                  \
  {                                                                            \
    asm volatile("s_waitcnt vmcnt(7)" ::: "memory");                           \
    __builtin_amdgcn_s_barrier();                                              \
    unsigned AH[4], AM[4], AL[4];                                              \
    split2(XA.x, XA.y, AH[0], AM[0], AL[0]);                                   \
    split2(XA.z, XA.w, AH[1], AM[1], AL[1]);                                   \
    split2(XB.x, XB.y, AH[2], AM[2], AL[2]);                                   \
    split2(XB.z, XB.w, AH[3], AM[3], AL[3]);                                   \
    s16x8 ah = pack8(AH), am = pack8(AM), al = pack8(AL);                      \
    const char* bb = gbuf + (PAR)*12288 + lane * 16;                           \
    _Pragma("unroll") for (int eg = 0; eg < 4; ++eg) {                         \
      s16x8 bh = *(const s16x8*)(bb + (eg * 3 + 0) * 1024);                    \
      s16x8 bm = *(const s16x8*)(bb + (eg * 3 + 1) * 1024);                    \
      s16x8 bl = *(const s16x8*)(bb + (eg * 3 + 2) * 1024);                    \
      accH[eg] = MFMA(ah, bh, accH[eg]);                                       \
      accC[eg] = MFMA(ah, bm, accC[eg]);                                       \
      accC[eg] = MFMA(am, bh, accC[eg]);                                       \
      accC[eg] = MFMA(am, bm, accC[eg]);                                       \
      accC[eg] = MFMA(ah, bl, accC[eg]);                                       \
      accC[eg] = MFMA(al, bh, accC[eg]);                                       \
    }                                                                          \
    __builtin_amdgcn_s_barrier();                                              \
    asm volatile("" ::: "memory");                                             \
    {                                                                          \
      int kn = (I) + 2 > 31 ? 31 : (I) + 2;                                    \
      stage3(wfg, kn, gbuf + (PAR)*12288, sw, lane);                           \
    }                                                                          \
    asm volatile("" ::: "memory");                                             \
    {                                                                          \
      int kn = (I) + 4 > 31 ? 31 : (I) + 4;                                    \
      XA = ((const float4*)(xr + kn * 32))[0];                                 \
      XB = ((const float4*)(xr + kn * 32))[1];                                 \
    }                                                                          \
    asm volatile("" ::: "memory");                                             \
  }

#pragma unroll 1
  for (int i = 0; i < 32; i += 4) {
    GBODY(x0a, x0b, 0, i);
    GBODY(x1a, x1b, 1, i + 1);
    GBODY(x2a, x2b, 0, i + 2);
    GBODY(x3a, x3b, 1, i + 3);
  }

  asm volatile("s_waitcnt vmcnt(0)" ::: "memory");
  __syncthreads();

  // per-group partial logits -> ltp[g][expert*68 + token]
  {
    float* ltp = smem + g * 4352;
#pragma unroll
    for (int eg = 0; eg < 4; ++eg) {
#pragma unroll
      for (int r = 0; r < 4; ++r) {
        ltp[(eg * 16 + (lane & 15)) * 68 + (sw << 4) + ((lane >> 4) << 2) + r] =
            accH[eg][r] + accC[eg][r];
      }
    }
  }
  __syncthreads();

  // combine 4 k-partials, unscale by 1/64
  for (int idx = tid; idx < 4352; idx += 1024)
    lt[idx] = (lt[idx] + smem[4352 + idx] + smem[8704 + idx] + smem[13056 + idx]) * 0.015625f;
  __syncthreads();

  // softmax per token (store p = exp(l-m) back)
  if (tid < 64) {
    const int t = tid;
    ce_lds[t] = 0.f;
    float m = -1e30f;
#pragma unroll 1
    for (int e = 0; e < 64; ++e) m = fmaxf(m, lt[e * 68 + t]);
    float ssum = 0.f;
#pragma unroll 1
    for (int e = 0; e < 64; ++e) {
      float p = expf(lt[e * 68 + t] - m);
      lt[e * 68 + t] = p;
      ssum += p;
    }
    inv_s[t] = 1.f / ssum;
  }
  __syncthreads();

  // pi partial: per-expert sum of scores
  if (tid < 64) {
    const int e = tid;
    float ssum = 0.f;
#pragma unroll 1
    for (int t = 0; t < 64; ++t) ssum += lt[e * 68 + t] * inv_s[t];
    atomicAdd(pi_g + e, ssum);
  }
  __syncthreads();

  // stable top-8 (strict > keeps lowest index on ties; descending)
  if (tid < 64) {
    const int t = tid;
    const float invv = inv_s[t];
    const size_t tg = (size_t)(tok0 + t);
#pragma unroll 1
    for (int r = 0; r < 8; ++r) {
      float bv = -1.f;
      int bi = 0;
#pragma unroll 1
      for (int e = 0; e < 64; ++e) {
        float p = lt[e * 68 + t];
        if (p > bv) { bv = p; bi = e; }
      }
      lt[bi * 68 + t] = -1.f;
      atomicAdd(ce_lds + bi, 1.f);
      out[tg * 8 + r] = (float)bi;
      out[(size_t)N * 8 + tg * 8 + r] = bv * invv;
    }
  }
  __syncthreads();
  if (tid < 64) atomicAdd(ce_g + tid, ce_lds[tid]);
}

// w [64][4096] -> fragment-ordered 3-way split blob, scaled by 64
__global__ void build_wfrag(const float* __restrict__ w, ushort* __restrict__ wf) {
  const int kb = blockIdx.x;  // 0..127
  const int t = threadIdx.x;  // 256
  const int eg = t >> 6, lane = t & 63;
  const int e = (eg << 4) + (lane & 15);
  const int k0 = (kb << 5) + ((lane >> 4) << 3);
  const float* src = w + (size_t)e * DDIM + k0;
  unsigned H[4], M[4], L[4];
#pragma unroll
  for (int i = 0; i < 4; ++i) {
    float a = src[2 * i] * 64.f, b = src[2 * i + 1] * 64.f;
    split2(a, b, H[i], M[i], L[i]);
  }
  const size_t base = ((size_t)kb * 12 + eg * 3) * 512 + (size_t)lane * 8;
  *(uint4*)(wf + base) = make_uint4(H[0], H[1], H[2], H[3]);
  *(uint4*)(wf + base + 512) = make_uint4(M[0], M[1], M[2], M[3]);
  *(uint4*)(wf + base + 1024) = make_uint4(L[0], L[1], L[2], L[3]);
}

__global__ void aux_final(const float* __restrict__ pi_g,
                          const float* __restrict__ ce_g,
                          float* __restrict__ out_aux, int N) {
  const int e = threadIdx.x;  // 64
  float v = (pi_g[e] / (float)N) * (ce_g[e] / ((float)N * 8.0f)) * 64.0f * 0.01f;
#pragma unroll
  for (int off = 32; off; off >>= 1) v += __shfl_down(v, off, 64);
  if (e == 0) *out_aux = v;
}

extern "C" void kernel_launch(void* const* d_in, const int* in_sizes, int n_in,
                              void* d_out, int out_size, void* d_ws, size_t ws_size,
                              hipStream_t stream) {
  (void)n_in; (void)out_size; (void)ws_size;
  const float* x = (const float*)d_in[0];
  const float* w = (const float*)d_in[1];
  float* out = (float*)d_out;
  const int N = in_sizes[0] / DDIM;  // 16384

  ushort* wf = (ushort*)d_ws;  // 128*12*512 ushorts = 1.5 MiB
  float* pi_g = (float*)((char*)d_ws + (size_t)128 * 12 * 512 * 2);
  float* ce_g = pi_g + 64;

  hipMemsetAsync(pi_g, 0, 128 * sizeof(float), stream);
  build_wfrag<<<128, 256, 0, stream>>>(w, wf);
  moe_gate_main<<<N / 64, 1024, 0, stream>>>(x, wf, out, pi_g, ce_g, N);
  aux_final<<<1, 64, 0, stream>>>(pi_g, ce_g, out + (size_t)N * 16, N);
}

// Round 5
// 118.034 us; speedup vs baseline: 4.4549x; 1.0082x over previous
//
#include <hip/hip_runtime.h>
#include <math.h>

#define DDIM 4096
#define NEXP 64

typedef short s16x8 __attribute__((ext_vector_type(8)));
typedef float f32x4 __attribute__((ext_vector_type(4)));

__device__ __forceinline__ unsigned cvt_pk_bf16(float a, float b) {
  unsigned r;
  asm("v_cvt_pk_bf16_f32 %0, %1, %2" : "=v"(r) : "v"(a), "v"(b));
  return r;  // lo16 = bf16(a), hi16 = bf16(b)
}

// 3-way bf16 split of two floats -> packed hi/mid/lo words
__device__ __forceinline__ void split2(float a, float b, unsigned& H,
                                       unsigned& M, unsigned& L) {
  H = cvt_pk_bf16(a, b);
  float h0 = __uint_as_float(H << 16);
  float h1 = __uint_as_float(H & 0xffff0000u);
  float r0 = a - h0, r1 = b - h1;
  M = cvt_pk_bf16(r0, r1);
  float m0 = __uint_as_float(M << 16);
  float m1 = __uint_as_float(M & 0xffff0000u);
  L = cvt_pk_bf16(r0 - m0, r1 - m1);
}

union U8 { unsigned u[4]; s16x8 v; };
__device__ __forceinline__ s16x8 pack8(const unsigned* a) {
  U8 t;
  t.u[0] = a[0]; t.u[1] = a[1]; t.u[2] = a[2]; t.u[3] = a[3];
  return t.v;
}

// stage this sub-wave's 3 of the 12 1KB B-fragment chunks for k-tile kb
__device__ __forceinline__ void stage3(const ushort* __restrict__ wf, int kb,
                                       char* dst, int sw, int lane) {
#pragma unroll
  for (int j = 0; j < 3; ++j) {
    const int c = sw * 3 + j;
    __builtin_amdgcn_global_load_lds(
        (const __attribute__((address_space(1))) void*)(wf + (size_t)(kb * 12 + c) * 512 + lane * 8),
        (__attribute__((address_space(3))) void*)(dst + c * 1024), 16, 0, 0);
  }
}

#define MFMA(A, B, C) __builtin_amdgcn_mfma_f32_16x16x32_bf16(A, B, C, 0, 0, 0)

// 16 waves: group g = wv>>2 owns k-range [g*1024, (g+1)*1024); sub-wave
// s = wv&3 owns tokens [s*16, s*16+16). Each group double-buffers its own
// 12KB B tile in LDS. x loaded global->VGPR 4 k-tiles deep.
// k-tile sweep ROTATED per (block, group) to spread simultaneous HBM reads
// across channel-interleave phases (x token rows are 16KB apart: channel
// bits come from k-offset only -> lockstep k == channel camping).
__global__ __launch_bounds__(1024) void moe_gate_main(
    const float* __restrict__ x,    // [N][4096]
    const ushort* __restrict__ wf,  // [128kb][4eg][3lvl][64lane][8] bf16 bits
    float* __restrict__ out,        // idx [N*8], w [N*8], aux
    float* __restrict__ pi_g, float* __restrict__ ce_g, int N) {
  __shared__ float smem[24576];  // 96 KB: GEMM = 4 groups x 2 x 12KB
  float* lt = smem;              // epilogue: final logits [64 e][stride 68]
  float* inv_s = smem + 17408;
  float* ce_lds = smem + 17472;

  const int tid = threadIdx.x;
  const int lane = tid & 63;
  const int wv = tid >> 6;   // 0..15
  const int g = wv >> 2;     // k-group
  const int sw = wv & 3;     // token sub-group
  const int tok0 = blockIdx.x << 6;
  const int rot = ((blockIdx.x * 9) + (g << 3)) & 31;

  char* gbuf = (char*)smem + g * 24576;  // this group's 2x12KB
  const float* xr = x + (size_t)(tok0 + (sw << 4) + (lane & 15)) * DDIM +
                    (g << 10) + ((lane >> 4) << 3);
  const ushort* wfg = wf + (size_t)g * 32 * 12 * 512;

  f32x4 accH[4], accC[4];
#pragma unroll
  for (int eg = 0; eg < 4; ++eg) {
#pragma unroll
    for (int r = 0; r < 4; ++r) { accH[eg][r] = 0.f; accC[eg][r] = 0.f; }
  }

  // prologue, FIFO order: S0, X0, X1, S1, X2, X3 (rotated tile indices)
  const int p1 = (rot + 1) & 31, p2 = (rot + 2) & 31, p3 = (rot + 3) & 31;
  stage3(wfg, rot, gbuf, sw, lane);
  asm volatile("" ::: "memory");
  float4 x0a = ((const float4*)(xr + rot * 32))[0];
  float4 x0b = ((const float4*)(xr + rot * 32))[1];
  float4 x1a = ((const float4*)(xr + p1 * 32))[0];
  float4 x1b = ((const float4*)(xr + p1 * 32))[1];
  asm volatile("" ::: "memory");
  stage3(wfg, p1, gbuf + 12288, sw, lane);
  asm volatile("" ::: "memory");
  float4 x2a = ((const float4*)(xr + p2 * 32))[0];
  float4 x2b = ((const float4*)(xr + p2 * 32))[1];
  float4 x3a = ((const float4*)(xr + p3 * 32))[0];
  float4 x3b = ((const float4*)(xr + p3 * 32))[1];
  asm volatile("" ::: "memory");

#define GBODY(XA, XB, PAR, I)                                                  \
  {                                                                            \
    asm volatile("s_waitcnt vmcnt(7)" ::: "memory");                           \
    __builtin_amdgcn_s_barrier();                                              \
    unsigned AH[4], AM[4], AL[4];                                              \
    split2(XA.x, XA.y, AH[0], AM[0], AL[0]);                                   \
    split2(XA.z, XA.w, AH[1], AM[1], AL[1]);                                   \
    split2(XB.x, XB.y, AH[2], AM[2], AL[2]);                                   \
    split2(XB.z, XB.w, AH[3], AM[3], AL[3]);                                   \
    s16x8 ah = pack8(AH), am = pack8(AM), al = pack8(AL);                      \
    const char* bb = gbuf + (PAR)*12288 + lane * 16;                           \
    _Pragma("unroll") for (int eg = 0; eg < 4; ++eg) {                         \
      s16x8 bh = *(const s16x8*)(bb + (eg * 3 + 0) * 1024);                    \
      s16x8 bm = *(const s16x8*)(bb + (eg * 3 + 1) * 1024);                    \
      s16x8 bl = *(const s16x8*)(bb + (eg * 3 + 2) * 1024);                    \
      accH[eg] = MFMA(ah, bh, accH[eg]);                                       \
      accC[eg] = MFMA(ah, bm, accC[eg]);                                       \
      accC[eg] = MFMA(am, bh, accC[eg]);                                       \
      accC[eg] = MFMA(am, bm, accC[eg]);                                       \
      accC[eg] = MFMA(ah, bl, accC[eg]);                                       \
      accC[eg] = MFMA(al, bh, accC[eg]);                                       \
    }                                                                          \
    __builtin_amdgcn_s_barrier();                                              \
    asm volatile("" ::: "memory");                                             \
    stage3(wfg, ((I) + 2 + rot) & 31, gbuf + (PAR)*12288, sw, lane);           \
    asm volatile("" ::: "memory");                                             \
    {                                                                          \
      const int kn = ((I) + 4 + rot) & 31;                                     \
      XA = ((const float4*)(xr + kn * 32))[0];                                 \
      XB = ((const float4*)(xr + kn * 32))[1];                                 \
    }                                                                          \
    asm volatile("" ::: "memory");                                             \
  }

#pragma unroll 1
  for (int i = 0; i < 32; i += 4) {
    GBODY(x0a, x0b, 0, i);
    GBODY(x1a, x1b, 1, i + 1);
    GBODY(x2a, x2b, 0, i + 2);
    GBODY(x3a, x3b, 1, i + 3);
  }

  asm volatile("s_waitcnt vmcnt(0)" ::: "memory");
  __syncthreads();

  // per-group partial logits -> ltp[g][expert*68 + token]
  {
    float* ltp = smem + g * 4352;
#pragma unroll
    for (int eg = 0; eg < 4; ++eg) {
#pragma unroll
      for (int r = 0; r < 4; ++r) {
        ltp[(eg * 16 + (lane & 15)) * 68 + (sw << 4) + ((lane >> 4) << 2) + r] =
            accH[eg][r] + accC[eg][r];
      }
    }
  }
  __syncthreads();

  // combine 4 k-partials, unscale by 1/64
  for (int idx = tid; idx < 4352; idx += 1024)
    lt[idx] = (lt[idx] + smem[4352 + idx] + smem[8704 + idx] + smem[13056 + idx]) * 0.015625f;
  __syncthreads();

  // softmax per token (store p = exp(l-m) back)
  if (tid < 64) {
    const int t = tid;
    ce_lds[t] = 0.f;
    float m = -1e30f;
#pragma unroll 1
    for (int e = 0; e < 64; ++e) m = fmaxf(m, lt[e * 68 + t]);
    float ssum = 0.f;
#pragma unroll 1
    for (int e = 0; e < 64; ++e) {
      float p = expf(lt[e * 68 + t] - m);
      lt[e * 68 + t] = p;
      ssum += p;
    }
    inv_s[t] = 1.f / ssum;
  }
  __syncthreads();

  // pi partial: per-expert sum of scores
  if (tid < 64) {
    const int e = tid;
    float ssum = 0.f;
#pragma unroll 1
    for (int t = 0; t < 64; ++t) ssum += lt[e * 68 + t] * inv_s[t];
    atomicAdd(pi_g + e, ssum);
  }
  __syncthreads();

  // stable top-8 (strict > keeps lowest index on ties; descending)
  if (tid < 64) {
    const int t = tid;
    const float invv = inv_s[t];
    const size_t tg = (size_t)(tok0 + t);
#pragma unroll 1
    for (int r = 0; r < 8; ++r) {
      float bv = -1.f;
      int bi = 0;
#pragma unroll 1
      for (int e = 0; e < 64; ++e) {
        float p = lt[e * 68 + t];
        if (p > bv) { bv = p; bi = e; }
      }
      lt[bi * 68 + t] = -1.f;
      atomicAdd(ce_lds + bi, 1.f);
      out[tg * 8 + r] = (float)bi;
      out[(size_t)N * 8 + tg * 8 + r] = bv * invv;
    }
  }
  __syncthreads();
  if (tid < 64) atomicAdd(ce_g + tid, ce_lds[tid]);
}

// w [64][4096] -> fragment-ordered 3-way split blob, scaled by 64
__global__ void build_wfrag(const float* __restrict__ w, ushort* __restrict__ wf) {
  const int kb = blockIdx.x;  // 0..127
  const int t = threadIdx.x;  // 256
  const int eg = t >> 6, lane = t & 63;
  const int e = (eg << 4) + (lane & 15);
  const int k0 = (kb << 5) + ((lane >> 4) << 3);
  const float* src = w + (size_t)e * DDIM + k0;
  unsigned H[4], M[4], L[4];
#pragma unroll
  for (int i = 0; i < 4; ++i) {
    float a = src[2 * i] * 64.f, b = src[2 * i + 1] * 64.f;
    split2(a, b, H[i], M[i], L[i]);
  }
  const size_t base = ((size_t)kb * 12 + eg * 3) * 512 + (size_t)lane * 8;
  *(uint4*)(wf + base) = make_uint4(H[0], H[1], H[2], H[3]);
  *(uint4*)(wf + base + 512) = make_uint4(M[0], M[1], M[2], M[3]);
  *(uint4*)(wf + base + 1024) = make_uint4(L[0], L[1], L[2], L[3]);
}

__global__ void aux_final(const float* __restrict__ pi_g,
                          const float* __restrict__ ce_g,
                          float* __restrict__ out_aux, int N) {
  const int e = threadIdx.x;  // 64
  float v = (pi_g[e] / (float)N) * (ce_g[e] / ((float)N * 8.0f)) * 64.0f * 0.01f;
#pragma unroll
  for (int off = 32; off; off >>= 1) v += __shfl_down(v, off, 64);
  if (e == 0) *out_aux = v;
}

extern "C" void kernel_launch(void* const* d_in, const int* in_sizes, int n_in,
                              void* d_out, int out_size, void* d_ws, size_t ws_size,
                              hipStream_t stream) {
  (void)n_in; (void)out_size; (void)ws_size;
  const float* x = (const float*)d_in[0];
  const float* w = (const float*)d_in[1];
  float* out = (float*)d_out;
  const int N = in_sizes[0] / DDIM;  // 16384

  ushort* wf = (ushort*)d_ws;  // 128*12*512 ushorts = 1.5 MiB
  float* pi_g = (float*)((char*)d_ws + (size_t)128 * 12 * 512 * 2);
  float* ce_g = pi_g + 64;

  hipMemsetAsync(pi_g, 0, 128 * sizeof(float), stream);
  build_wfrag<<<128, 256, 0, stream>>>(w, wf);
  moe_gate_main<<<N / 64, 1024, 0, stream>>>(x, wf, out, pi_g, ce_g, N);
  aux_final<<<1, 64, 0, stream>>>(pi_g, ce_g, out + (size_t)N * 16, N);
}